// Round 1
// baseline (27957.266 us; speedup 1.0000x reference)
//
#include <hip/hip_runtime.h>
#include <math.h>

// Problem constants (fixed by the reference)
constexpr int N_ = 50000;   // nodes
constexpr int E_ = 600000;  // edges per relation
constexpr int F_ = 256;     // feature dim
constexpr int H_ = 128;     // hidden dim
constexpr int Q_ = 64;      // query dim (== one wave)
constexpr int R_ = 2;       // relations
constexpr int L_ = 2;       // conv depth

#define MODE_STORE 0
#define MODE_TANH  1
#define MODE_ACC   2

// ---------------------------------------------------------------------------
// Tiled f32 GEMM: C[M x 64*gridDim.y] = A (M x K) * B
//   BT=true : C[n,j] = sum_k A[n,k] * B[j*ldb + k]   (B^T, row-major B)
//   BT=false: C[n,j] = sum_k A[n,k] * B[k*ldb + j]
// rowscale (optional): multiply row n of the result by rowscale[n]
// mode: store / tanh(store) / accumulate
// Tile: 64x64, BK=16, 256 threads, 4x4 outputs/thread.
// ---------------------------------------------------------------------------
template <bool BT>
__global__ __launch_bounds__(256) void gemm_kernel(
    const float* __restrict__ A, int lda,
    const float* __restrict__ B, int ldb,
    float* __restrict__ C, int ldc,
    int M, int K,
    const float* __restrict__ rowscale, int mode)
{
    __shared__ __align__(16) float As[16][68];  // stride 68: 16B-aligned rows, padded
    __shared__ __align__(16) float Bs[16][68];

    const int row0 = blockIdx.x * 64;
    const int col0 = blockIdx.y * 64;
    const int tid  = threadIdx.x;
    const int tm = tid >> 4;     // 0..15
    const int tn = tid & 15;     // 0..15

    float acc[4][4] = {};

    for (int kk = 0; kk < K; kk += 16) {
        {   // A tile: 64 rows x 16 k, one float4 per thread
            const int m  = tid >> 2;
            const int k4 = (tid & 3) * 4;
            const int r  = row0 + m;
            float4 v = make_float4(0.f, 0.f, 0.f, 0.f);
            if (r < M) v = *(const float4*)(A + (size_t)r * lda + kk + k4);
            As[k4 + 0][m] = v.x; As[k4 + 1][m] = v.y;
            As[k4 + 2][m] = v.z; As[k4 + 3][m] = v.w;
        }
        if (BT) {  // B[j*ldb + k]
            const int j  = tid >> 2;
            const int k4 = (tid & 3) * 4;
            float4 v = *(const float4*)(B + (size_t)(col0 + j) * ldb + kk + k4);
            Bs[k4 + 0][j] = v.x; Bs[k4 + 1][j] = v.y;
            Bs[k4 + 2][j] = v.z; Bs[k4 + 3][j] = v.w;
        } else {   // B[k*ldb + j]
            const int k  = tid >> 4;
            const int j4 = (tid & 15) * 4;
            float4 v = *(const float4*)(B + (size_t)(kk + k) * ldb + col0 + j4);
            Bs[k][j4 + 0] = v.x; Bs[k][j4 + 1] = v.y;
            Bs[k][j4 + 2] = v.z; Bs[k][j4 + 3] = v.w;
        }
        __syncthreads();

        #pragma unroll
        for (int k = 0; k < 16; k++) {
            const float4 av = *(const float4*)&As[k][tm * 4];
            const float4 bv = *(const float4*)&Bs[k][tn * 4];
            const float a[4] = {av.x, av.y, av.z, av.w};
            const float b[4] = {bv.x, bv.y, bv.z, bv.w};
            #pragma unroll
            for (int i = 0; i < 4; i++)
                #pragma unroll
                for (int j = 0; j < 4; j++)
                    acc[i][j] += a[i] * b[j];
        }
        __syncthreads();
    }

    #pragma unroll
    for (int i = 0; i < 4; i++) {
        const int r = row0 + tm * 4 + i;
        if (r >= M) continue;
        const float rs = rowscale ? rowscale[r] : 1.0f;
        #pragma unroll
        for (int j = 0; j < 4; j++) {
            const int c = col0 + tn * 4 + j;
            float v = acc[i][j] * rs;
            if (mode == MODE_TANH) v = tanhf(v);
            float* p = C + (size_t)r * ldc + c;
            if (mode == MODE_ACC) *p += v;
            else                  *p = v;
        }
    }
}

// ---------------------------------------------------------------------------
// Zero-fill (float4 granularity)
// ---------------------------------------------------------------------------
__global__ __launch_bounds__(256) void zero_f4(float4* __restrict__ p, int n4)
{
    int t = blockIdx.x * 256 + threadIdx.x;
    if (t < n4) p[t] = make_float4(0.f, 0.f, 0.f, 0.f);
}

// ---------------------------------------------------------------------------
// Degree counting (float atomics; exact for counts << 2^24)
// ---------------------------------------------------------------------------
__global__ __launch_bounds__(256) void deg_count(const int* __restrict__ idx,
                                                 float* __restrict__ deg, int nE)
{
    int t = blockIdx.x * 256 + threadIdx.x;
    if (t < nE) atomicAdd(&deg[idx[t]], 1.0f);
}

// deg -> (max(deg,1))^-0.5
__global__ __launch_bounds__(256) void deg_finalize(float* __restrict__ deg, int n)
{
    int t = blockIdx.x * 256 + threadIdx.x;
    if (t < n) {
        float v = deg[t];
        deg[t] = rsqrtf(v < 1.0f ? 1.0f : v);
    }
}

// ---------------------------------------------------------------------------
// Edge scatter: agg[dst[e], :] += m[src[e], :]
// 32 lanes per edge, float4 gather + 4 float atomics per lane.
// ---------------------------------------------------------------------------
__global__ __launch_bounds__(256) void scatter_add(
    const float* __restrict__ m, const int* __restrict__ src,
    const int* __restrict__ dst, float* __restrict__ agg, int nE)
{
    int t = blockIdx.x * 256 + threadIdx.x;
    int e = t >> 5;
    if (e >= nE) return;
    int c = (t & 31) << 2;
    int s = src[e], d = dst[e];
    const float4 v = *(const float4*)(m + (size_t)s * H_ + c);
    float* o = agg + (size_t)d * H_ + c;
    atomicAdd(o + 0, v.x);
    atomicAdd(o + 1, v.y);
    atomicAdd(o + 2, v.z);
    atomicAdd(o + 3, v.w);
}

// ---------------------------------------------------------------------------
// Fused GCN finalize + relation attention + combine.
// hs_r[n,i] = agg_r[n,i] * deg_in_r[n]^-0.5 + bias_r[i]   (computed on the fly)
// score_r[n] = sum_q tanh(b1[q] + sum_i hs_r[n,i]*W1[i,q]) * w2[q]
// a = softmax_r(score);  out[n,:] = a0*hs_0[n,:] + a1*hs_1[n,:]
// One wave (64 lanes = 64 q-indices) per node.
// ---------------------------------------------------------------------------
__global__ __launch_bounds__(256) void attn_kernel(
    const float* __restrict__ agg0, const float* __restrict__ agg1,
    const float* __restrict__ si0,  const float* __restrict__ si1,
    const float* __restrict__ bias0, const float* __restrict__ bias1,
    const float* __restrict__ W1, const float* __restrict__ b1,
    const float* __restrict__ w2, float* __restrict__ outb, int n)
{
    __shared__ float W1s[H_ * Q_];   // 32 KiB
    __shared__ float b1s[Q_], w2s[Q_], bA[H_], bB[H_];

    for (int i = threadIdx.x; i < H_ * Q_; i += 256) W1s[i] = W1[i];
    if (threadIdx.x < Q_) { b1s[threadIdx.x] = b1[threadIdx.x]; w2s[threadIdx.x] = w2[threadIdx.x]; }
    if (threadIdx.x < H_) bA[threadIdx.x] = bias0[threadIdx.x];
    else if (threadIdx.x < 2 * H_) bB[threadIdx.x - H_] = bias1[threadIdx.x - H_];
    __syncthreads();

    const int lane   = threadIdx.x & 63;
    const int wave   = (blockIdx.x * 256 + threadIdx.x) >> 6;
    const int nwaves = gridDim.x * 4;

    for (int node = wave; node < n; node += nwaves) {
        const float s0 = si0[node];
        const float s1 = si1[node];
        const float* r0 = agg0 + (size_t)node * H_;
        const float* r1 = agg1 + (size_t)node * H_;

        float t0 = b1s[lane], t1 = b1s[lane];
        #pragma unroll 4
        for (int i = 0; i < H_; i++) {
            const float w = W1s[i * Q_ + lane];
            t0 += (r0[i] * s0 + bA[i]) * w;
            t1 += (r1[i] * s1 + bB[i]) * w;
        }
        float sc0 = tanhf(t0) * w2s[lane];
        float sc1 = tanhf(t1) * w2s[lane];
        #pragma unroll
        for (int off = 32; off > 0; off >>= 1) {
            sc0 += __shfl_xor(sc0, off);
            sc1 += __shfl_xor(sc1, off);
        }
        const float mx = fmaxf(sc0, sc1);
        const float e0 = expf(sc0 - mx), e1 = expf(sc1 - mx);
        const float a0 = e0 / (e0 + e1), a1 = 1.0f - a0;

        const float o0 = a0 * (r0[lane] * s0 + bA[lane])
                       + a1 * (r1[lane] * s1 + bB[lane]);
        const float o1 = a0 * (r0[lane + 64] * s0 + bA[lane + 64])
                       + a1 * (r1[lane + 64] * s1 + bB[lane + 64]);
        outb[(size_t)node * H_ + lane]      = o0;
        outb[(size_t)node * H_ + 64 + lane] = o1;
    }
}

// ---------------------------------------------------------------------------
// Orchestration
// ---------------------------------------------------------------------------
extern "C" void kernel_launch(void* const* d_in, const int* in_sizes, int n_in,
                              void* d_out, int out_size, void* d_ws, size_t ws_size,
                              hipStream_t stream)
{
    const float* x_attr    = (const float*)d_in[0];
    const float* x_stru    = (const float*)d_in[1];
    const int*   e_attr    = (const int*)d_in[2];
    const int*   e_stru    = (const int*)d_in[3];
    const float* Wf        = (const float*)d_in[4];
    const float* convW     = (const float*)d_in[5];
    const float* convB     = (const float*)d_in[6];
    const float* aW1       = (const float*)d_in[7];
    const float* aB1       = (const float*)d_in[8];
    const float* aW2       = (const float*)d_in[9];
    const float* Wc        = (const float*)d_in[10];
    float*       out       = (float*)d_out;
    float*       ws        = (float*)d_ws;

    const size_t NH = (size_t)N_ * H_;
    float* B_h0  = ws;            // h0  (also reused for h2)
    float* B_hA  = ws + 1 * NH;   // h1 / hA
    float* B_hs0 = ws + 2 * NH;   // relation-0 aggregate
    float* B_hs1 = ws + 3 * NH;   // relation-1 aggregate
    float* B_m   = ws + 4 * NH;   // pre-scatter messages
    float* dscale = ws + 5 * NH;  // [so0, si0, so1, si1], each N_ floats

    const int GX = (N_ + 63) / 64;                 // gemm grid rows
    const dim3 GGRID(GX, 2);                       // 128 output cols
    const int ZB_NH  = (int)((NH / 4 + 255) / 256);
    const int ZB_DEG = ((4 * N_) / 4 + 255) / 256;
    const int DEG_B  = (E_ + 255) / 256;
    const int SC_B   = (E_ * 32) / 256;

    for (int run = 0; run < 4; run++) {
        const int sign = run >> 1;
        const float* x = (run & 1) ? x_stru : x_attr;
        const int* edges = (run & 1) ? e_stru : e_attr;
        float* y = out + (size_t)run * NH;
        const float* WcS = Wc + (size_t)sign * H_ * 3 * H_;

        // --- degrees: [so0, si0, so1, si1] -> clamped rsqrt ---
        zero_f4<<<ZB_DEG, 256, 0, stream>>>((float4*)dscale, (4 * N_) / 4);
        for (int r = 0; r < R_; r++) {
            const int* srcp = edges + ((size_t)(sign * R_ + r) * 2 + 0) * E_;
            const int* dstp = srcp + E_;
            deg_count<<<DEG_B, 256, 0, stream>>>(srcp, dscale + (2 * r) * N_, E_);
            deg_count<<<DEG_B, 256, 0, stream>>>(dstp, dscale + (2 * r + 1) * N_, E_);
        }
        deg_finalize<<<(4 * N_ + 255) / 256, 256, 0, stream>>>(dscale, 4 * N_);

        // --- h0 = tanh(x @ Wf^T) ---
        gemm_kernel<true><<<GGRID, 256, 0, stream>>>(
            x, F_, Wf + (size_t)sign * H_ * F_, F_, B_h0, H_, N_, F_, nullptr, MODE_TANH);

        // --- y = h0 @ Wc[:, 0:H]^T ---
        gemm_kernel<true><<<GGRID, 256, 0, stream>>>(
            B_h0, H_, WcS, 3 * H_, y, H_, N_, H_, nullptr, MODE_STORE);

        // --- heterogeneous layer helper ---
        auto het = [&](const float* h_in, int l, float* outb) {
            for (int r = 0; r < R_; r++) {
                const float* W = convW + ((size_t)(sign * L_ + l) * R_ + r) * H_ * H_;
                gemm_kernel<false><<<GGRID, 256, 0, stream>>>(
                    h_in, H_, W, H_, B_m, H_, N_, H_, dscale + (2 * r) * N_, MODE_STORE);
                float* agg = r ? B_hs1 : B_hs0;
                zero_f4<<<ZB_NH, 256, 0, stream>>>((float4*)agg, (int)(NH / 4));
                const int* srcp = edges + ((size_t)(sign * R_ + r) * 2 + 0) * E_;
                const int* dstp = srcp + E_;
                scatter_add<<<SC_B, 256, 0, stream>>>(B_m, srcp, dstp, agg, E_);
            }
            const size_t lo = (size_t)(sign * L_ + l);
            attn_kernel<<<2048, 256, 0, stream>>>(
                B_hs0, B_hs1, dscale + N_, dscale + 3 * N_,
                convB + (lo * R_ + 0) * H_, convB + (lo * R_ + 1) * H_,
                aW1 + lo * H_ * Q_, aB1 + lo * Q_, aW2 + lo * Q_, outb, N_);
        };

        // --- h1 = het(h0, layer 1); y += h1 @ Wc[:, H:2H]^T ---
        het(B_h0, 1, B_hA);
        gemm_kernel<true><<<GGRID, 256, 0, stream>>>(
            B_hA, H_, WcS + H_, 3 * H_, y, H_, N_, H_, nullptr, MODE_ACC);

        // --- hA = het(h0, layer 0) ---
        het(B_h0, 0, B_hA);

        // --- h2 = het(hA, layer 1) (h0 buffer is free now); y += h2 @ Wc[:, 2H:3H]^T ---
        het(B_hA, 1, B_h0);
        gemm_kernel<true><<<GGRID, 256, 0, stream>>>(
            B_h0, H_, WcS + 2 * H_, 3 * H_, y, H_, N_, H_, nullptr, MODE_ACC);
    }
}

// Round 2
// 5435.642 us; speedup vs baseline: 5.1433x; 5.1433x over previous
//
#include <hip/hip_runtime.h>
#include <math.h>

// Problem constants (fixed by the reference)
constexpr int N_ = 50000;   // nodes
constexpr int E_ = 600000;  // edges per relation
constexpr int F_ = 256;     // feature dim
constexpr int H_ = 128;     // hidden dim
constexpr int Q_ = 64;      // query dim (== one wave)
constexpr int R_ = 2;       // relations
constexpr int L_ = 2;       // conv depth

#define MODE_STORE 0
#define MODE_TANH  1
#define MODE_ACC   2

// ---------------------------------------------------------------------------
// Tiled f32 GEMM: C[M x 64*gridDim.y] = A (M x K) * B
//   BT=true : C[n,j] = sum_k A[n,k] * B[j*ldb + k]   (B^T, row-major B)
//   BT=false: C[n,j] = sum_k A[n,k] * B[k*ldb + j]
// rowscale (optional): multiply row n of the result by rowscale[n]
// Tile: 64x64, BK=16, 256 threads, 4x4 outputs/thread.
// ---------------------------------------------------------------------------
template <bool BT>
__global__ __launch_bounds__(256) void gemm_kernel(
    const float* __restrict__ A, int lda,
    const float* __restrict__ B, int ldb,
    float* __restrict__ C, int ldc,
    int M, int K,
    const float* __restrict__ rowscale, int mode)
{
    __shared__ __align__(16) float As[16][68];
    __shared__ __align__(16) float Bs[16][68];

    const int row0 = blockIdx.x * 64;
    const int col0 = blockIdx.y * 64;
    const int tid  = threadIdx.x;
    const int tm = tid >> 4;
    const int tn = tid & 15;

    float acc[4][4] = {};

    for (int kk = 0; kk < K; kk += 16) {
        {   // A tile: 64 rows x 16 k, one float4 per thread
            const int m  = tid >> 2;
            const int k4 = (tid & 3) * 4;
            const int r  = row0 + m;
            float4 v = make_float4(0.f, 0.f, 0.f, 0.f);
            if (r < M) v = *(const float4*)(A + (size_t)r * lda + kk + k4);
            As[k4 + 0][m] = v.x; As[k4 + 1][m] = v.y;
            As[k4 + 2][m] = v.z; As[k4 + 3][m] = v.w;
        }
        if (BT) {
            const int j  = tid >> 2;
            const int k4 = (tid & 3) * 4;
            float4 v = *(const float4*)(B + (size_t)(col0 + j) * ldb + kk + k4);
            Bs[k4 + 0][j] = v.x; Bs[k4 + 1][j] = v.y;
            Bs[k4 + 2][j] = v.z; Bs[k4 + 3][j] = v.w;
        } else {
            const int k  = tid >> 4;
            const int j4 = (tid & 15) * 4;
            float4 v = *(const float4*)(B + (size_t)(kk + k) * ldb + col0 + j4);
            Bs[k][j4 + 0] = v.x; Bs[k][j4 + 1] = v.y;
            Bs[k][j4 + 2] = v.z; Bs[k][j4 + 3] = v.w;
        }
        __syncthreads();

        #pragma unroll
        for (int k = 0; k < 16; k++) {
            const float4 av = *(const float4*)&As[k][tm * 4];
            const float4 bv = *(const float4*)&Bs[k][tn * 4];
            const float a[4] = {av.x, av.y, av.z, av.w};
            const float b[4] = {bv.x, bv.y, bv.z, bv.w};
            #pragma unroll
            for (int i = 0; i < 4; i++)
                #pragma unroll
                for (int j = 0; j < 4; j++)
                    acc[i][j] += a[i] * b[j];
        }
        __syncthreads();
    }

    #pragma unroll
    for (int i = 0; i < 4; i++) {
        const int r = row0 + tm * 4 + i;
        if (r >= M) continue;
        const float rs = rowscale ? rowscale[r] : 1.0f;
        #pragma unroll
        for (int j = 0; j < 4; j++) {
            const int c = col0 + tn * 4 + j;
            float v = acc[i][j] * rs;
            if (mode == MODE_TANH) v = tanhf(v);
            float* p = C + (size_t)r * ldc + c;
            if (mode == MODE_ACC) *p += v;
            else                  *p = v;
        }
    }
}

// ---------------------------------------------------------------------------
// Zero ints
// ---------------------------------------------------------------------------
__global__ __launch_bounds__(256) void zero_i(int* __restrict__ p, int n)
{
    int t = blockIdx.x * 256 + threadIdx.x;
    if (t < n) p[t] = 0;
}

// ---------------------------------------------------------------------------
// Degree counting: eb is the contiguous (R,2,E) int block for this sign.
// cnt layout: [which = r*2 + (0=src/out,1=dst/in)] x N
// ---------------------------------------------------------------------------
__global__ __launch_bounds__(256) void count_deg(const int* __restrict__ eb,
                                                 int* __restrict__ cnt, int total)
{
    int t = blockIdx.x * 256 + threadIdx.x;
    if (t >= total) return;
    int which = t / E_;
    atomicAdd(&cnt[which * N_ + eb[t]], 1);
}

// dscale[i] = rsqrt(max(cnt[i],1))
__global__ __launch_bounds__(256) void deg_finalize(const int* __restrict__ cnt,
                                                    float* __restrict__ dscale, int n)
{
    int t = blockIdx.x * 256 + threadIdx.x;
    if (t < n) {
        int v = cnt[t];
        dscale[t] = rsqrtf((float)(v < 1 ? 1 : v));
    }
}

// ---------------------------------------------------------------------------
// Exclusive scan of in-degree counts -> CSR offsets. One block per relation.
// input: cnt + (2r+1)*N ; output: offs + r*(N+1)
// ---------------------------------------------------------------------------
__global__ __launch_bounds__(256) void scan2(const int* __restrict__ cnt,
                                             int* __restrict__ offs)
{
    __shared__ int buf[256];
    __shared__ int carry_s;
    const int r = blockIdx.x;
    const int* in = cnt + (size_t)(2 * r + 1) * N_;
    int* out = offs + (size_t)r * (N_ + 1);

    if (threadIdx.x == 0) carry_s = 0;
    __syncthreads();
    for (int base = 0; base < N_; base += 256) {
        int i = base + threadIdx.x;
        int v = (i < N_) ? in[i] : 0;
        buf[threadIdx.x] = v;
        __syncthreads();
        #pragma unroll
        for (int d = 1; d < 256; d <<= 1) {
            int t = (threadIdx.x >= d) ? buf[threadIdx.x - d] : 0;
            __syncthreads();
            buf[threadIdx.x] += t;
            __syncthreads();
        }
        if (i < N_) out[i] = carry_s + buf[threadIdx.x] - v;
        __syncthreads();
        if (threadIdx.x == 255) carry_s += buf[255];
        __syncthreads();
    }
    if (threadIdx.x == 0) out[N_] = carry_s;
}

// cursor[r*N + i] = offs[r*(N+1) + i]
__global__ __launch_bounds__(256) void cursor_init(const int* __restrict__ offs,
                                                   int* __restrict__ cursor, int n2)
{
    int t = blockIdx.x * 256 + threadIdx.x;
    if (t >= n2) return;
    int r = (t >= N_) ? 1 : 0;
    int i = t - r * N_;
    cursor[t] = offs[(size_t)r * (N_ + 1) + i];
}

// csr[r*E + pos] = src, bucketed by dst
__global__ __launch_bounds__(256) void csr_fill(const int* __restrict__ eb,
                                                int* __restrict__ cursor,
                                                int* __restrict__ csr, int total)
{
    int t = blockIdx.x * 256 + threadIdx.x;
    if (t >= total) return;
    int r = (t >= E_) ? 1 : 0;
    int e = t - r * E_;
    int s = eb[(r * 2 + 0) * E_ + e];
    int d = eb[(r * 2 + 1) * E_ + e];
    int pos = atomicAdd(&cursor[r * N_ + d], 1);
    csr[(size_t)r * E_ + pos] = s;
}

// ---------------------------------------------------------------------------
// Fused: CSR pull (both relations) + GCN finalize + relation attention.
// One wave per node; lane l holds columns {2l, 2l+1} as a float2.
//   hs_r = (sum_{e in-edges} m_r[src_e]) * deg_in_r^-0.5 + bias_r
//   score_r = sum_q tanh(b1[q] + sum_i hs_r[i] W1[i,q]) w2[q]
//   out = softmax_r(score) . hs
// ---------------------------------------------------------------------------
__global__ __launch_bounds__(256) void pull_attn(
    const float2* __restrict__ m0, const float2* __restrict__ m1,
    const int* __restrict__ offs0, const int* __restrict__ csr0,
    const int* __restrict__ offs1, const int* __restrict__ csr1,
    const float* __restrict__ si0, const float* __restrict__ si1,
    const float* __restrict__ bias0, const float* __restrict__ bias1,
    const float* __restrict__ W1, const float* __restrict__ b1,
    const float* __restrict__ w2, float2* __restrict__ outb, int n)
{
    __shared__ float W1s[H_ * Q_];          // 32 KiB, layout [i*64 + q]
    __shared__ float2 hsS[4][2][Q_];        // per-wave hs staging, 4 KiB
    __shared__ float b1s[Q_], w2s[Q_], bAs[H_], bBs[H_];

    for (int i = threadIdx.x; i < H_ * Q_; i += 256) W1s[i] = W1[i];
    if (threadIdx.x < Q_) { b1s[threadIdx.x] = b1[threadIdx.x]; w2s[threadIdx.x] = w2[threadIdx.x]; }
    if (threadIdx.x < H_) bAs[threadIdx.x] = bias0[threadIdx.x];
    else bBs[threadIdx.x - H_] = bias1[threadIdx.x - H_];
    __syncthreads();

    const int lane = threadIdx.x & 63;
    const int wv   = threadIdx.x >> 6;
    int node = (blockIdx.x * 256 + threadIdx.x) >> 6;
    node = __builtin_amdgcn_readfirstlane(node);   // wave-uniform -> scalar loads

    float2 hs0 = make_float2(0.f, 0.f), hs1 = hs0;

    if (node < n) {
        float2 a0 = make_float2(0.f, 0.f), a1 = a0;
        const int b0 = offs0[node], e0 = offs0[node + 1];
        for (int k = b0; k < e0; k++) {
            const int s = csr0[k];
            const float2 v = m0[(size_t)s * 64 + lane];
            a0.x += v.x; a0.y += v.y;
        }
        const int b1i = offs1[node], e1 = offs1[node + 1];
        for (int k = b1i; k < e1; k++) {
            const int s = csr1[k];
            const float2 v = m1[(size_t)s * 64 + lane];
            a1.x += v.x; a1.y += v.y;
        }
        const float sc0 = si0[node], sc1 = si1[node];
        hs0.x = a0.x * sc0 + bAs[2 * lane];
        hs0.y = a0.y * sc0 + bAs[2 * lane + 1];
        hs1.x = a1.x * sc1 + bBs[2 * lane];
        hs1.y = a1.y * sc1 + bBs[2 * lane + 1];
        hsS[wv][0][lane] = hs0;
        hsS[wv][1][lane] = hs1;
    }
    __syncthreads();

    if (node < n) {
        const float* h0p = (const float*)&hsS[wv][0][0];
        const float* h1p = (const float*)&hsS[wv][1][0];
        float t0 = b1s[lane], t1 = b1s[lane];
        #pragma unroll 8
        for (int i = 0; i < H_; i++) {
            const float wval = W1s[i * Q_ + lane];
            t0 += h0p[i] * wval;
            t1 += h1p[i] * wval;
        }
        float s0 = tanhf(t0) * w2s[lane];
        float s1 = tanhf(t1) * w2s[lane];
        #pragma unroll
        for (int off = 32; off > 0; off >>= 1) {
            s0 += __shfl_xor(s0, off);
            s1 += __shfl_xor(s1, off);
        }
        const float mx = fmaxf(s0, s1);
        const float e0v = expf(s0 - mx), e1v = expf(s1 - mx);
        const float a0 = e0v / (e0v + e1v), a1 = 1.0f - a0;

        float2 o;
        o.x = a0 * hs0.x + a1 * hs1.x;
        o.y = a0 * hs0.y + a1 * hs1.y;
        outb[(size_t)node * 64 + lane] = o;
    }
}

// ---------------------------------------------------------------------------
// Orchestration
// ---------------------------------------------------------------------------
extern "C" void kernel_launch(void* const* d_in, const int* in_sizes, int n_in,
                              void* d_out, int out_size, void* d_ws, size_t ws_size,
                              hipStream_t stream)
{
    const float* x_attr = (const float*)d_in[0];
    const float* x_stru = (const float*)d_in[1];
    const int*   e_attr = (const int*)d_in[2];
    const int*   e_stru = (const int*)d_in[3];
    const float* Wf     = (const float*)d_in[4];
    const float* convW  = (const float*)d_in[5];
    const float* convB  = (const float*)d_in[6];
    const float* aW1    = (const float*)d_in[7];
    const float* aB1    = (const float*)d_in[8];
    const float* aW2    = (const float*)d_in[9];
    const float* Wc     = (const float*)d_in[10];
    float*       out    = (float*)d_out;
    float*       ws     = (float*)d_ws;

    const size_t NH = (size_t)N_ * H_;
    float* A  = ws;            // h0, later h2
    float* Bb = ws + 1 * NH;   // h1, later hA
    float* C  = ws + 2 * NH;   // m0
    float* D  = ws + 3 * NH;   // m1
    float* dscale = ws + 4 * NH;                    // 4N floats [out0,in0,out1,in1]
    int*   ibase  = (int*)(dscale + 4 * N_);
    int*   cnt    = ibase;                          // 4N ints (reused as cursor)
    int*   offs   = ibase + 4 * N_;                 // 2*(N+1)
    int*   csr    = offs + 2 * (N_ + 1);            // 2*E

    const int GX = (N_ + 63) / 64;
    const dim3 GGRID(GX, 2);
    const int PA_B = (N_ * 64) / 256;               // pull_attn blocks (N % 4 == 0)

    for (int run = 0; run < 4; run++) {
        const int sign = run >> 1;
        const float* x = (run & 1) ? x_stru : x_attr;
        const int* eb = ((run & 1) ? e_stru : e_attr) + (size_t)sign * (R_ * 2 * E_);
        float* y = out + (size_t)run * NH;
        const float* WcS = Wc + (size_t)sign * H_ * 3 * H_;

        // --- degrees + CSR build (once per run, reused by all 3 layers) ---
        zero_i<<<(4 * N_ + 255) / 256, 256, 0, stream>>>(cnt, 4 * N_);
        count_deg<<<(4 * E_ + 255) / 256, 256, 0, stream>>>(eb, cnt, 4 * E_);
        deg_finalize<<<(4 * N_ + 255) / 256, 256, 0, stream>>>(cnt, dscale, 4 * N_);
        scan2<<<2, 256, 0, stream>>>(cnt, offs);
        cursor_init<<<(2 * N_ + 255) / 256, 256, 0, stream>>>(offs, cnt, 2 * N_);
        csr_fill<<<(2 * E_ + 255) / 256, 256, 0, stream>>>(eb, cnt, csr, 2 * E_);

        // --- h0 = tanh(x @ Wf^T) ---
        gemm_kernel<true><<<GGRID, 256, 0, stream>>>(
            x, F_, Wf + (size_t)sign * H_ * F_, F_, A, H_, N_, F_, nullptr, MODE_TANH);

        // --- y = h0 @ Wc[:, 0:H]^T ---
        gemm_kernel<true><<<GGRID, 256, 0, stream>>>(
            A, H_, WcS, 3 * H_, y, H_, N_, H_, nullptr, MODE_STORE);

        // --- heterogeneous layer: m GEMMs + fused pull/attention ---
        auto het = [&](const float* h_in, int l, float* outb) {
            const size_t lo = (size_t)(sign * L_ + l);
            for (int r = 0; r < R_; r++) {
                const float* W = convW + (lo * R_ + r) * H_ * H_;
                gemm_kernel<false><<<GGRID, 256, 0, stream>>>(
                    h_in, H_, W, H_, r ? D : C, H_, N_, H_,
                    dscale + (size_t)(2 * r) * N_, MODE_STORE);
            }
            pull_attn<<<PA_B, 256, 0, stream>>>(
                (const float2*)C, (const float2*)D,
                offs, csr, offs + (N_ + 1), csr + E_,
                dscale + N_, dscale + 3 * N_,
                convB + (lo * R_ + 0) * H_, convB + (lo * R_ + 1) * H_,
                aW1 + lo * H_ * Q_, aB1 + lo * Q_, aW2 + lo * Q_,
                (float2*)outb, N_);
        };

        // --- h1 = het(h0, layer 1); y += h1 @ Wc[:, H:2H]^T ---
        het(A, 1, Bb);
        gemm_kernel<true><<<GGRID, 256, 0, stream>>>(
            Bb, H_, WcS + H_, 3 * H_, y, H_, N_, H_, nullptr, MODE_ACC);

        // --- hA = het(h0, layer 0) (h1 consumed, reuse Bb) ---
        het(A, 0, Bb);

        // --- h2 = het(hA, layer 1) -> A (h0 dead); y += h2 @ Wc[:, 2H:3H]^T ---
        het(Bb, 1, A);
        gemm_kernel<true><<<GGRID, 256, 0, stream>>>(
            A, H_, WcS + 2 * H_, 3 * H_, y, H_, N_, H_, nullptr, MODE_ACC);
    }
}

// Round 3
// 5101.354 us; speedup vs baseline: 5.4804x; 1.0655x over previous
//
#include <hip/hip_runtime.h>
#include <math.h>

// Problem constants (fixed by the reference)
constexpr int N_ = 50000;   // nodes
constexpr int E_ = 600000;  // edges per relation
constexpr int F_ = 256;     // feature dim
constexpr int H_ = 128;     // hidden dim
constexpr int Q_ = 64;      // query dim (== one wave)
constexpr int R_ = 2;       // relations
constexpr int L_ = 2;       // conv depth

#define MODE_STORE 0
#define MODE_TANH  1
#define MODE_ACC   2

// ---------------------------------------------------------------------------
// Tiled f32 GEMM: C[M x 64*gridDim.y] = A (M x K) * B
//   BT=true : C[n,j] = sum_k A[n,k] * B[j*ldb + k]   (B^T, row-major B)
//   BT=false: C[n,j] = sum_k A[n,k] * B[k*ldb + j]
// rowscale (optional): multiply row n of the result by rowscale[n]
// Tile: 64x64, BK=16, 256 threads, 4x4 outputs/thread.
// ---------------------------------------------------------------------------
template <bool BT>
__global__ __launch_bounds__(256) void gemm_kernel(
    const float* __restrict__ A, int lda,
    const float* __restrict__ B, int ldb,
    float* __restrict__ C, int ldc,
    int M, int K,
    const float* __restrict__ rowscale, int mode)
{
    __shared__ __align__(16) float As[16][68];
    __shared__ __align__(16) float Bs[16][68];

    const int row0 = blockIdx.x * 64;
    const int col0 = blockIdx.y * 64;
    const int tid  = threadIdx.x;
    const int tm = tid >> 4;
    const int tn = tid & 15;

    float acc[4][4] = {};

    for (int kk = 0; kk < K; kk += 16) {
        {   // A tile: 64 rows x 16 k, one float4 per thread
            const int m  = tid >> 2;
            const int k4 = (tid & 3) * 4;
            const int r  = row0 + m;
            float4 v = make_float4(0.f, 0.f, 0.f, 0.f);
            if (r < M) v = *(const float4*)(A + (size_t)r * lda + kk + k4);
            As[k4 + 0][m] = v.x; As[k4 + 1][m] = v.y;
            As[k4 + 2][m] = v.z; As[k4 + 3][m] = v.w;
        }
        if (BT) {
            const int j  = tid >> 2;
            const int k4 = (tid & 3) * 4;
            float4 v = *(const float4*)(B + (size_t)(col0 + j) * ldb + kk + k4);
            Bs[k4 + 0][j] = v.x; Bs[k4 + 1][j] = v.y;
            Bs[k4 + 2][j] = v.z; Bs[k4 + 3][j] = v.w;
        } else {
            const int k  = tid >> 4;
            const int j4 = (tid & 15) * 4;
            float4 v = *(const float4*)(B + (size_t)(kk + k) * ldb + col0 + j4);
            Bs[k][j4 + 0] = v.x; Bs[k][j4 + 1] = v.y;
            Bs[k][j4 + 2] = v.z; Bs[k][j4 + 3] = v.w;
        }
        __syncthreads();

        #pragma unroll
        for (int k = 0; k < 16; k++) {
            const float4 av = *(const float4*)&As[k][tm * 4];
            const float4 bv = *(const float4*)&Bs[k][tn * 4];
            const float a[4] = {av.x, av.y, av.z, av.w};
            const float b[4] = {bv.x, bv.y, bv.z, bv.w};
            #pragma unroll
            for (int i = 0; i < 4; i++)
                #pragma unroll
                for (int j = 0; j < 4; j++)
                    acc[i][j] += a[i] * b[j];
        }
        __syncthreads();
    }

    #pragma unroll
    for (int i = 0; i < 4; i++) {
        const int r = row0 + tm * 4 + i;
        if (r >= M) continue;
        const float rs = rowscale ? rowscale[r] : 1.0f;
        #pragma unroll
        for (int j = 0; j < 4; j++) {
            const int c = col0 + tn * 4 + j;
            float v = acc[i][j] * rs;
            if (mode == MODE_TANH) v = tanhf(v);
            float* p = C + (size_t)r * ldc + c;
            if (mode == MODE_ACC) *p += v;
            else                  *p = v;
        }
    }
}

// ---------------------------------------------------------------------------
// Zero ints
// ---------------------------------------------------------------------------
__global__ __launch_bounds__(256) void zero_i(int* __restrict__ p, int n)
{
    int t = blockIdx.x * 256 + threadIdx.x;
    if (t < n) p[t] = 0;
}

// ---------------------------------------------------------------------------
// Degree counting: eb is the contiguous (R,2,E) int block for this sign.
// cnt layout: [which = r*2 + (0=src/out,1=dst/in)] x N
// ---------------------------------------------------------------------------
__global__ __launch_bounds__(256) void count_deg(const int* __restrict__ eb,
                                                 int* __restrict__ cnt, int total)
{
    int t = blockIdx.x * 256 + threadIdx.x;
    if (t >= total) return;
    int which = t / E_;
    atomicAdd(&cnt[which * N_ + eb[t]], 1);
}

// dscale[i] = rsqrt(max(cnt[i],1))
__global__ __launch_bounds__(256) void deg_finalize(const int* __restrict__ cnt,
                                                    float* __restrict__ dscale, int n)
{
    int t = blockIdx.x * 256 + threadIdx.x;
    if (t < n) {
        int v = cnt[t];
        dscale[t] = rsqrtf((float)(v < 1 ? 1 : v));
    }
}

// ---------------------------------------------------------------------------
// Exclusive scan of in-degree counts -> CSR offsets + cursor init.
// One block of 1024 threads per relation. Each thread owns a contiguous
// ~49-element chunk: serial chunk sum -> one 1024-wide LDS scan -> serial
// chunk prefix write. Replaces the 196-sequential-chunk scan (212 us -> ~10).
// input: cnt + (2r+1)*N ; outputs: offs + r*(N+1), cursor + r*N
// ---------------------------------------------------------------------------
__global__ __launch_bounds__(1024) void scan_offs(const int* __restrict__ cnt,
                                                  int* __restrict__ offs,
                                                  int* __restrict__ cursor)
{
    __shared__ int part[1024];
    const int r = blockIdx.x;
    const int* in = cnt + (size_t)(2 * r + 1) * N_;
    int* out = offs + (size_t)r * (N_ + 1);
    int* cur = cursor + (size_t)r * N_;

    constexpr int CH = (N_ + 1023) / 1024;   // 49
    const int lo = threadIdx.x * CH;
    const int hi = (lo + CH < N_) ? lo + CH : N_;

    int s = 0;
    for (int i = lo; i < hi; i++) s += in[i];
    part[threadIdx.x] = s;
    __syncthreads();

    #pragma unroll
    for (int d = 1; d < 1024; d <<= 1) {
        int t = (threadIdx.x >= d) ? part[threadIdx.x - d] : 0;
        __syncthreads();
        part[threadIdx.x] += t;
        __syncthreads();
    }

    int run = part[threadIdx.x] - s;   // exclusive prefix at chunk start
    for (int i = lo; i < hi; i++) {
        int v = in[i];
        out[i] = run;
        cur[i] = run;
        run += v;
    }
    if (threadIdx.x == 1023) out[N_] = run;
}

// csr[r*E + pos] = src, bucketed by dst
__global__ __launch_bounds__(256) void csr_fill(const int* __restrict__ eb,
                                                int* __restrict__ cursor,
                                                int* __restrict__ csr, int total)
{
    int t = blockIdx.x * 256 + threadIdx.x;
    if (t >= total) return;
    int r = (t >= E_) ? 1 : 0;
    int e = t - r * E_;
    int s = eb[(r * 2 + 0) * E_ + e];
    int d = eb[(r * 2 + 1) * E_ + e];
    int pos = atomicAdd(&cursor[r * N_ + d], 1);
    csr[(size_t)r * E_ + pos] = s;
}

// ---------------------------------------------------------------------------
// Fused: CSR pull (both relations) + GCN finalize + relation attention.
// One wave per node; lane l holds columns {2l, 2l+1} as a float2.
//   hs_r = (sum_{e in-edges} m_r[src_e]) * deg_in_r^-0.5 + bias_r
//   score_r = sum_q tanh(b1[q] + sum_i hs_r[i] W1[i,q]) w2[q]
//   out = softmax_r(score) . hs
// ---------------------------------------------------------------------------
__global__ __launch_bounds__(256) void pull_attn(
    const float2* __restrict__ m0, const float2* __restrict__ m1,
    const int* __restrict__ offs0, const int* __restrict__ csr0,
    const int* __restrict__ offs1, const int* __restrict__ csr1,
    const float* __restrict__ si0, const float* __restrict__ si1,
    const float* __restrict__ bias0, const float* __restrict__ bias1,
    const float* __restrict__ W1, const float* __restrict__ b1,
    const float* __restrict__ w2, float2* __restrict__ outb, int n)
{
    __shared__ float W1s[H_ * Q_];          // 32 KiB, layout [i*64 + q]
    __shared__ float2 hsS[4][2][Q_];        // per-wave hs staging, 4 KiB
    __shared__ float b1s[Q_], w2s[Q_], bAs[H_], bBs[H_];

    for (int i = threadIdx.x; i < H_ * Q_; i += 256) W1s[i] = W1[i];
    if (threadIdx.x < Q_) { b1s[threadIdx.x] = b1[threadIdx.x]; w2s[threadIdx.x] = w2[threadIdx.x]; }
    if (threadIdx.x < H_) bAs[threadIdx.x] = bias0[threadIdx.x];
    else bBs[threadIdx.x - H_] = bias1[threadIdx.x - H_];
    __syncthreads();

    const int lane = threadIdx.x & 63;
    const int wv   = threadIdx.x >> 6;
    int node = (blockIdx.x * 256 + threadIdx.x) >> 6;
    node = __builtin_amdgcn_readfirstlane(node);   // wave-uniform -> scalar loads

    float2 hs0 = make_float2(0.f, 0.f), hs1 = hs0;

    if (node < n) {
        float2 a0 = make_float2(0.f, 0.f), a1 = a0;
        const int b0 = offs0[node], e0 = offs0[node + 1];
        for (int k = b0; k < e0; k++) {
            const int s = csr0[k];
            const float2 v = m0[(size_t)s * 64 + lane];
            a0.x += v.x; a0.y += v.y;
        }
        const int b1i = offs1[node], e1 = offs1[node + 1];
        for (int k = b1i; k < e1; k++) {
            const int s = csr1[k];
            const float2 v = m1[(size_t)s * 64 + lane];
            a1.x += v.x; a1.y += v.y;
        }
        const float sc0 = si0[node], sc1 = si1[node];
        hs0.x = a0.x * sc0 + bAs[2 * lane];
        hs0.y = a0.y * sc0 + bAs[2 * lane + 1];
        hs1.x = a1.x * sc1 + bBs[2 * lane];
        hs1.y = a1.y * sc1 + bBs[2 * lane + 1];
        hsS[wv][0][lane] = hs0;
        hsS[wv][1][lane] = hs1;
    }
    __syncthreads();

    if (node < n) {
        const float* h0p = (const float*)&hsS[wv][0][0];
        const float* h1p = (const float*)&hsS[wv][1][0];
        float t0 = b1s[lane], t1 = b1s[lane];
        #pragma unroll 8
        for (int i = 0; i < H_; i++) {
            const float wval = W1s[i * Q_ + lane];
            t0 += h0p[i] * wval;
            t1 += h1p[i] * wval;
        }
        float s0 = tanhf(t0) * w2s[lane];
        float s1 = tanhf(t1) * w2s[lane];
        #pragma unroll
        for (int off = 32; off > 0; off >>= 1) {
            s0 += __shfl_xor(s0, off);
            s1 += __shfl_xor(s1, off);
        }
        const float mx = fmaxf(s0, s1);
        const float e0v = expf(s0 - mx), e1v = expf(s1 - mx);
        const float a0 = e0v / (e0v + e1v), a1 = 1.0f - a0;

        float2 o;
        o.x = a0 * hs0.x + a1 * hs1.x;
        o.y = a0 * hs0.y + a1 * hs1.y;
        outb[(size_t)node * 64 + lane] = o;
    }
}

// ---------------------------------------------------------------------------
// Orchestration
// ---------------------------------------------------------------------------
extern "C" void kernel_launch(void* const* d_in, const int* in_sizes, int n_in,
                              void* d_out, int out_size, void* d_ws, size_t ws_size,
                              hipStream_t stream)
{
    const float* x_attr = (const float*)d_in[0];
    const float* x_stru = (const float*)d_in[1];
    const int*   e_attr = (const int*)d_in[2];
    const int*   e_stru = (const int*)d_in[3];
    const float* Wf     = (const float*)d_in[4];
    const float* convW  = (const float*)d_in[5];
    const float* convB  = (const float*)d_in[6];
    const float* aW1    = (const float*)d_in[7];
    const float* aB1    = (const float*)d_in[8];
    const float* aW2    = (const float*)d_in[9];
    const float* Wc     = (const float*)d_in[10];
    float*       out    = (float*)d_out;
    float*       ws     = (float*)d_ws;

    const size_t NH = (size_t)N_ * H_;
    float* A  = ws;            // h0, later h2
    float* Bb = ws + 1 * NH;   // h1, later hA
    float* C  = ws + 2 * NH;   // m0
    float* D  = ws + 3 * NH;   // m1
    float* dscale = ws + 4 * NH;                    // 4N floats [out0,in0,out1,in1]
    int*   ibase  = (int*)(dscale + 4 * N_);
    int*   cnt    = ibase;                          // 4N ints
    int*   offs   = ibase + 4 * N_;                 // 2*(N+1)
    int*   csr    = offs + 2 * (N_ + 1);            // 2*E
    int*   cursor = csr + 2 * E_;                   // 2*N

    const int GX = (N_ + 63) / 64;
    const dim3 GGRID(GX, 2);
    const int PA_B = (N_ * 64) / 256;               // pull_attn blocks (N % 4 == 0)

    for (int run = 0; run < 4; run++) {
        const int sign = run >> 1;
        const float* x = (run & 1) ? x_stru : x_attr;
        const int* eb = ((run & 1) ? e_stru : e_attr) + (size_t)sign * (R_ * 2 * E_);
        float* y = out + (size_t)run * NH;
        const float* WcS = Wc + (size_t)sign * H_ * 3 * H_;

        // --- degrees + CSR build (once per run, reused by all 3 layers) ---
        zero_i<<<(4 * N_ + 255) / 256, 256, 0, stream>>>(cnt, 4 * N_);
        count_deg<<<(4 * E_ + 255) / 256, 256, 0, stream>>>(eb, cnt, 4 * E_);
        deg_finalize<<<(4 * N_ + 255) / 256, 256, 0, stream>>>(cnt, dscale, 4 * N_);
        scan_offs<<<2, 1024, 0, stream>>>(cnt, offs, cursor);
        csr_fill<<<(2 * E_ + 255) / 256, 256, 0, stream>>>(eb, cursor, csr, 2 * E_);

        // --- h0 = tanh(x @ Wf^T) ---
        gemm_kernel<true><<<GGRID, 256, 0, stream>>>(
            x, F_, Wf + (size_t)sign * H_ * F_, F_, A, H_, N_, F_, nullptr, MODE_TANH);

        // --- y = h0 @ Wc[:, 0:H]^T ---
        gemm_kernel<true><<<GGRID, 256, 0, stream>>>(
            A, H_, WcS, 3 * H_, y, H_, N_, H_, nullptr, MODE_STORE);

        // --- heterogeneous layer: m GEMMs + fused pull/attention ---
        auto het = [&](const float* h_in, int l, float* outb) {
            const size_t lo = (size_t)(sign * L_ + l);
            for (int r = 0; r < R_; r++) {
                const float* W = convW + (lo * R_ + r) * H_ * H_;
                gemm_kernel<false><<<GGRID, 256, 0, stream>>>(
                    h_in, H_, W, H_, r ? D : C, H_, N_, H_,
                    dscale + (size_t)(2 * r) * N_, MODE_STORE);
            }
            pull_attn<<<PA_B, 256, 0, stream>>>(
                (const float2*)C, (const float2*)D,
                offs, csr, offs + (N_ + 1), csr + E_,
                dscale + N_, dscale + 3 * N_,
                convB + (lo * R_ + 0) * H_, convB + (lo * R_ + 1) * H_,
                aW1 + lo * H_ * Q_, aB1 + lo * Q_, aW2 + lo * Q_,
                (float2*)outb, N_);
        };

        // --- h1 = het(h0, layer 1); y += h1 @ Wc[:, H:2H]^T ---
        het(A, 1, Bb);
        gemm_kernel<true><<<GGRID, 256, 0, stream>>>(
            Bb, H_, WcS + H_, 3 * H_, y, H_, N_, H_, nullptr, MODE_ACC);

        // --- hA = het(h0, layer 0) (h1 consumed, reuse Bb) ---
        het(A, 0, Bb);

        // --- h2 = het(hA, layer 1) -> A (h0 dead); y += h2 @ Wc[:, 2H:3H]^T ---
        het(Bb, 1, A);
        gemm_kernel<true><<<GGRID, 256, 0, stream>>>(
            A, H_, WcS + 2 * H_, 3 * H_, y, H_, N_, H_, nullptr, MODE_ACC);
    }
}